// Round 17
// baseline (120.699 us; speedup 1.0000x reference)
//
#include <hip/hip_runtime.h>

constexpr int L = 128;
constexpr int NVOX = L * L * L;                     // 2,097,152
constexpr size_t TAB_BYTES = (size_t)NVOX * 16;     // 32 MB packed table
constexpr int SORT_N = 2048;
constexpr int RANK_BLOCKS = SORT_N / 256;           // 8
constexpr int TAB_BLOCKS = (NVOX / 2) / 256;        // 4096 (one thread = z-pair)

union HU { unsigned short u; _Float16 h; };
typedef _Float16 h2v __attribute__((ext_vector_type(2)));
union H2U { unsigned int u; h2v h; };

__device__ __forceinline__ unsigned int pack2(float a, float b) {
    HU x, y; x.h = (_Float16)a; y.h = (_Float16)b;
    return (unsigned int)x.u | ((unsigned int)y.u << 16);
}
__device__ __forceinline__ h2v u2h2(unsigned int w) { H2U c; c.u = w; return c.h; }

// 16B entry = full 2x2x2 fp16 stencil at base (x,y,z)  -> ONE gather/pixel.
// 64B line = 4 entries = {x,x+1} x {y} x {z,z+1}: the x-z pairing merges the
// plane slab's z-crossings (R16's measured line-count lever) while keeping
// R15's single-gather transaction economics.
__device__ __forceinline__ int brick16(int x, int y, int z) {
    return ((z >> 1) << 15) | (y << 8) | ((x >> 1) << 2) | ((z & 1) << 1) | (x & 1);
}

// ---- orientation key: Morton(octahedral(plane normal)) | index -------------
__device__ __forceinline__ unsigned part5(unsigned x) {   // 5-bit bit-spread
    x &= 0x1F;
    x = (x | (x << 4)) & 0x0F0Fu;
    x = (x | (x << 2)) & 0x3333u;
    x = (x | (x << 1)) & 0x5555u;
    return x;
}

__device__ __forceinline__ unsigned make_key(const float* __restrict__ R, int i)
{
    // plane normal = r0 x r2 (rows of R: r0 = j-direction, r2 = k-direction)
    float nx = R[1] * R[8] - R[2] * R[7];
    float ny = R[2] * R[6] - R[0] * R[8];
    float nz = R[0] * R[7] - R[1] * R[6];
    if (nz < 0.0f) { nx = -nx; ny = -ny; nz = -nz; }   // antipode fold
    const float s = fabsf(nx) + fabsf(ny) + nz + 1e-30f;
    const float u = nx / s, v = ny / s;                // octahedral hemisphere
    const int qu = min(max((int)((u * 0.5f + 0.5f) * 32.0f), 0), 31);
    const int qv = min(max((int)((v * 0.5f + 0.5f) * 32.0f), 0), 31);
    const unsigned morton = (part5((unsigned)qv) << 1) | part5((unsigned)qu);
    return (morton << 11) | (unsigned)i;               // unique -> deterministic
}

// ---- merged pre-pass -------------------------------------------------------
// Blocks 0..7 (FIRST, overlaps the build): parallel rank-sort -> perm.
// Blocks 8..4103: build the table; one thread fills a z-PAIR of 16B entries so
// every touched 64B line is written entirely within one block.
__global__ __launch_bounds__(256) void build_tab_sort(
    const float* __restrict__ vol, uint4* __restrict__ T,
    const float* __restrict__ rotmat, int* __restrict__ perm, int B, int do_sort)
{
    const int bid = blockIdx.x;
    const int tid = threadIdx.x;

    if (bid < RANK_BLOCKS) {
        if (!do_sort) return;
        __shared__ unsigned keys[SORT_N];
        #pragma unroll
        for (int h = 0; h < SORT_N / 256; ++h) {
            const int i = tid + h * 256;
            keys[i] = (i < B) ? make_key(rotmat + i * 9, i) : 0xFFFFFFFFu;
        }
        __syncthreads();
        const int img = (bid << 8) + tid;
        if (img < B) {
            const unsigned mykey = keys[img];
            int rank = 0;
            for (int j = 0; j < SORT_N; ++j)   // LDS broadcast scan
                rank += (keys[j] < mykey) ? 1 : 0;
            perm[rank] = img;
        }
        return;
    }

    const int e = (bid - RANK_BLOCKS) * 256 + tid;     // 0..NVOX/2-1: (x,y,zp)
    const int x  = e & 127, y = (e >> 7) & 127, zp = e >> 14;
    const int z0 = zp << 1, z1 = z0 | 1;
    const int x1 = min(x + 1, 127);
    const int ro0 = (y << 7), ro1 = (min(y + 1, 127) << 7);
    const float* __restrict__ p0 = vol + (z0 << 14);
    const float* __restrict__ p1 = vol + (z1 << 14);
    const float* __restrict__ p2 = vol + (min(z1 + 1, 127) << 14);
    uint4 a, b;
    a.x = pack2(p0[ro0 | x], p0[ro0 | x1]);
    a.y = pack2(p0[ro1 | x], p0[ro1 | x1]);
    a.z = pack2(p1[ro0 | x], p1[ro0 | x1]);
    a.w = pack2(p1[ro1 | x], p1[ro1 | x1]);
    b.x = a.z;
    b.y = a.w;
    b.z = pack2(p2[ro0 | x], p2[ro0 | x1]);
    b.w = pack2(p2[ro1 | x], p2[ro1 | x1]);
    T[brick16(x, y, z0)] = a;
    T[brick16(x, y, z1)] = b;
}

// ---------------- packed-table main kernel ----------------
struct Px {
    int e;            // bricked table index (clamped base corner)
    h2v wab;          // (xa,xb) as half2 -> fdot2 with table words
    float ya, yb, za, zb;
};

// slow path: full OOB/mask handling (edges of volume, annulus boundary)
__device__ __forceinline__ Px setup_slow(float gx, float gy, float gz, bool vis)
{
    Px p;
    const float fx0 = floorf(gx), fy0 = floorf(gy), fz0 = floorf(gz);
    const int ix = (int)fx0, iy = (int)fy0, iz = (int)fz0;
    const float fx = gx - fx0, fy = gy - fy0, fz = gz - fz0;

    const float wx0 = ((unsigned)ix       < 128u) ? 1.0f - fx : 0.0f;
    const float wx1 = ((unsigned)(ix + 1) < 128u) ? fx        : 0.0f;
    const float wy0 = ((unsigned)iy       < 128u) ? 1.0f - fy : 0.0f;
    const float wy1 = ((unsigned)(iy + 1) < 128u) ? fy        : 0.0f;
    const float wz0 = ((unsigned)iz       < 128u) ? 1.0f - fz : 0.0f;
    const float wz1 = ((unsigned)(iz + 1) < 128u) ? fz        : 0.0f;

    // map corner weights onto entry slots at clamp(i,0,127)
    const float xa = (ix == -1) ? wx1 : wx0;
    const float xb = (ix == -1) ? 0.0f : wx1;
    p.wab = h2v{(_Float16)xa, (_Float16)xb};
    p.ya = (iy == -1) ? wy1 : wy0;  p.yb = (iy == -1) ? 0.0f : wy1;
    p.za = (iz == -1) ? wz1 : wz0;  p.zb = (iz == -1) ? 0.0f : wz1;
    if (!vis) { p.za = 0.0f; p.zb = 0.0f; }           // circular mask

    const bool alive = vis && (ix >= -1) && (ix <= 127) && (iy >= -1)
                           && (iy <= 127) && (iz >= -1) && (iz <= 127);
    const int xe = min(max(ix, 0), 127);
    const int ye = min(max(iy, 0), 127);
    const int ze = min(max(iz, 0), 127);
    p.e = alive ? brick16(xe, ye, ze) : 0;            // dead -> line 0
    return p;
}

// fast path: fully interior and visible -> no selects/clamps
__device__ __forceinline__ Px setup_fast(float gx, float gy, float gz)
{
    Px p;
    const float fx0 = floorf(gx), fy0 = floorf(gy), fz0 = floorf(gz);
    const float fx = gx - fx0, fy = gy - fy0, fz = gz - fz0;
    p.wab = h2v{(_Float16)(1.0f - fx), (_Float16)fx};
    p.ya = 1.0f - fy;  p.yb = fy;
    p.za = 1.0f - fz;  p.zb = fz;
    p.e = brick16((int)fx0, (int)fy0, (int)fz0);
    return p;
}

__device__ __forceinline__ float combine_px(const Px& p, uint4 W)
{
    const float r0 = p.ya * __builtin_amdgcn_fdot2(u2h2(W.x), p.wab, 0.0f, false)
                   + p.yb * __builtin_amdgcn_fdot2(u2h2(W.y), p.wab, 0.0f, false);
    const float r1 = p.ya * __builtin_amdgcn_fdot2(u2h2(W.z), p.wab, 0.0f, false)
                   + p.yb * __builtin_amdgcn_fdot2(u2h2(W.w), p.wab, 0.0f, false);
    return p.za * r0 + p.zb * r1;
}

// 1D grid + XCD-affine mapping over SORTED image order (R13: -23%).
__global__ __launch_bounds__(256) void xfel_proj_t(
    const float* __restrict__ rotmat,          // [B,3,3]
    const uint4* __restrict__ T,               // packed stencil table
    float* __restrict__ out,                   // [B,L,L]
    const int* __restrict__ perm,              // sorted pos -> image (or null)
    int nimg_per_xcd)                          // B/8 (0 -> identity mapping)
{
    const int n = blockIdx.x;
    int b, t;
    if (nimg_per_xcd > 0) {
        const int xcd = n & 7;
        const int s   = n >> 3;
        b = perm[xcd * nimg_per_xcd + (s >> 4)];
        t = s & 15;
    } else {
        b = n >> 4;
        t = n & 15;
    }

    const int tid  = threadIdx.x;
    const int lane = tid & 63;
    const int wv   = tid >> 6;                    // 0..3
    const int k    = ((t & 1) << 6) | lane;
    const int j0   = ((t >> 1) << 4) + (wv << 2); // rows j0..j0+3

    const int obase = (b * L + j0) * L + k;

    // circular mask
    const float stepw = 128.0f / 127.0f;
    const float ak  = (float)(k - 64) * stepw;
    const float ak2 = ak * ak;
    const float thr = 57.6f * 57.6f;              // (0.9*L/2)^2

    bool vis[4];
    bool all_vis = true, any_vis = false;
    #pragma unroll
    for (int m = 0; m < 4; ++m) {
        const float aj = (float)(j0 + m - 64) * stepw;
        vis[m] = (aj * aj + ak2 < thr);
        any_vis |= vis[m];
        all_vis &= vis[m];
    }
    if (__ballot((int)any_vis) == 0ull) {         // whole wave masked
        #pragma unroll
        for (int m = 0; m < 4; ++m)
            __builtin_nontemporal_store(0.0f, out + obase + m * L);
        return;
    }

    // rotation is block-uniform -> scalar loads
    const float* __restrict__ R = rotmat + b * 9;
    const float R00 = R[0], R01 = R[1], R02 = R[2];
    const float R10 = R[3], R11 = R[4], R12 = R[5];
    const float R20 = R[6], R21 = R[7], R22 = R[8];

    const float lk  = -1.0f + (float)k * (2.0f / 127.0f);
    const float yc  = -1.0f + 64.0f * (2.0f / 127.0f);  // lin[64]
    const float lj0 = -1.0f + (float)j0 * (2.0f / 127.0f);

    // voxel coords of row j0; per-row increment is exactly (R00,R01,R02)
    float gx = (lj0 * R00 + yc * R10 + lk * R20 + 1.0f) * 63.5f;
    float gy = (lj0 * R01 + yc * R11 + lk * R21 + 1.0f) * 63.5f;
    float gz = (lj0 * R02 + yc * R12 + lk * R22 + 1.0f) * 63.5f;

    // interior test: rows 0 and 3 bound the linear walk
    const float gx3 = gx + 3.0f * R00, gy3 = gy + 3.0f * R01, gz3 = gz + 3.0f * R02;
    const bool intr = all_vis
        && (gx  >= 0.0f) && (gx  < 127.0f) && (gx3 >= 0.0f) && (gx3 < 127.0f)
        && (gy  >= 0.0f) && (gy  < 127.0f) && (gy3 >= 0.0f) && (gy3 < 127.0f)
        && (gz  >= 0.0f) && (gz  < 127.0f) && (gz3 >= 0.0f) && (gz3 < 127.0f);

    Px p[4];
    if (__ballot((int)intr) == ~0ull) {
        // wave fully interior+visible (~93% of live waves)
        #pragma unroll
        for (int m = 0; m < 4; ++m) {
            p[m] = setup_fast(gx, gy, gz);
            gx += R00; gy += R01; gz += R02;
        }
    } else {
        bool any_alive = false;
        #pragma unroll
        for (int m = 0; m < 4; ++m) {
            p[m] = setup_slow(gx, gy, gz, vis[m]);
            any_alive |= (p[m].e != 0);
            gx += R00; gy += R01; gz += R02;
        }
        if (__ballot((int)any_alive) == 0ull) {   // whole wave dead
            #pragma unroll
            for (int m = 0; m < 4; ++m)
                __builtin_nontemporal_store(0.0f, out + obase + m * L);
            return;
        }
    }

    // 4 stencil gathers (ONE per pixel), all in flight before consumption
    uint4 W[4];
    #pragma unroll
    for (int m = 0; m < 4; ++m) W[m] = T[p[m].e];

    __builtin_amdgcn_sched_barrier(0);

    #pragma unroll
    for (int m = 0; m < 4; ++m) {
        const float res = combine_px(p[m], W[m]);
        __builtin_nontemporal_store(res, out + obase + m * L);
    }
}

// ---------------- fp32 fallback (R6 kernel) for small ws_size ----------------
typedef float f2v __attribute__((ext_vector_type(2), aligned(4)));

struct PxF {
    int b00, b01, b10, b11, xe;
    float wa, wb, wy0, wy1, wz0, wz1;
    bool alive;
};

__device__ __forceinline__ PxF setup_pxf(float gx, float gy, float gz, bool vis)
{
    PxF p;
    const float fx0 = floorf(gx), fy0 = floorf(gy), fz0 = floorf(gz);
    const int ix = (int)fx0, iy = (int)fy0, iz = (int)fz0;
    const float fx = gx - fx0, fy = gy - fy0, fz = gz - fz0;
    const float wx0 = ((unsigned)ix       < 128u) ? 1.0f - fx : 0.0f;
    const float wx1 = ((unsigned)(ix + 1) < 128u) ? fx        : 0.0f;
    p.wa = (ix == -1) ? wx1 : ((ix == 127) ? 0.0f : wx0);
    p.wb = (ix == 127) ? wx0 : ((ix == -1) ? 0.0f : wx1);
    p.wy0 = ((unsigned)iy       < 128u) ? 1.0f - fy : 0.0f;
    p.wy1 = ((unsigned)(iy + 1) < 128u) ? fy        : 0.0f;
    p.wz0 = (vis && (unsigned)iz       < 128u) ? 1.0f - fz : 0.0f;
    p.wz1 = (vis && (unsigned)(iz + 1) < 128u) ? fz        : 0.0f;
    p.alive = vis && (ix >= -1) && (ix <= 127) && (iy >= -1) && (iy <= 127)
                  && (iz >= -1) && (iz <= 127);
    int xe = min(max(ix, 0), 126);
    int y0 = min(max(iy, 0), 127), y1 = min(max(iy + 1, 0), 127);
    int z0 = min(max(iz, 0), 127), z1 = min(max(iz + 1, 0), 127);
    if (!p.alive) { xe = 0; y0 = 0; y1 = 0; z0 = 0; z1 = 0; }
    p.xe  = xe;
    p.b00 = (z0 << 14) | (y0 << 7);
    p.b01 = (z0 << 14) | (y1 << 7);
    p.b10 = (z1 << 14) | (y0 << 7);
    p.b11 = (z1 << 14) | (y1 << 7);
    return p;
}

__global__ __launch_bounds__(256) void xfel_proj_f(
    const float* __restrict__ rotmat,
    const float* __restrict__ vol,
    float* __restrict__ out)
{
    const int tid  = threadIdx.x;
    const int lane = tid & 63;
    const int wv   = tid >> 6;
    const int t    = blockIdx.x;
    const int b    = blockIdx.y;
    const int k    = ((t & 1) << 6) | lane;
    const int j0   = ((t >> 1) << 4) + (wv << 2);
    const int obase = (b * L + j0) * L + k;

    const float stepw = 128.0f / 127.0f;
    const float ak  = (float)(k - 64) * stepw;
    const float ak2 = ak * ak;
    const float thr = 57.6f * 57.6f;

    bool vis[4]; bool any_vis = false;
    #pragma unroll
    for (int m = 0; m < 4; ++m) {
        const float aj = (float)(j0 + m - 64) * stepw;
        vis[m] = (aj * aj + ak2 < thr);
        any_vis |= vis[m];
    }
    if (__ballot((int)any_vis) == 0ull) {
        #pragma unroll
        for (int m = 0; m < 4; ++m)
            __builtin_nontemporal_store(0.0f, out + obase + m * L);
        return;
    }

    const float* __restrict__ R = rotmat + b * 9;
    const float R00 = R[0], R01 = R[1], R02 = R[2];
    const float R10 = R[3], R11 = R[4], R12 = R[5];
    const float R20 = R[6], R21 = R[7], R22 = R[8];
    const float lk  = -1.0f + (float)k * (2.0f / 127.0f);
    const float yc  = -1.0f + 64.0f * (2.0f / 127.0f);
    const float lj0 = -1.0f + (float)j0 * (2.0f / 127.0f);

    float gx = (lj0 * R00 + yc * R10 + lk * R20 + 1.0f) * 63.5f;
    float gy = (lj0 * R01 + yc * R11 + lk * R21 + 1.0f) * 63.5f;
    float gz = (lj0 * R02 + yc * R12 + lk * R22 + 1.0f) * 63.5f;

    PxF p[4]; bool any_alive = false;
    #pragma unroll
    for (int m = 0; m < 4; ++m) {
        p[m] = setup_pxf(gx, gy, gz, vis[m]);
        any_alive |= p[m].alive;
        gx += R00; gy += R01; gz += R02;
    }
    if (__ballot((int)any_alive) == 0ull) {
        #pragma unroll
        for (int m = 0; m < 4; ++m)
            __builtin_nontemporal_store(0.0f, out + obase + m * L);
        return;
    }

    f2v v[4][4];
    #pragma unroll
    for (int m = 0; m < 4; ++m) {
        v[m][0] = *(const f2v*)(vol + p[m].b00 + p[m].xe);
        v[m][1] = *(const f2v*)(vol + p[m].b01 + p[m].xe);
        v[m][2] = *(const f2v*)(vol + p[m].b10 + p[m].xe);
        v[m][3] = *(const f2v*)(vol + p[m].b11 + p[m].xe);
    }
    __builtin_amdgcn_sched_barrier(0);

    #pragma unroll
    for (int m = 0; m < 4; ++m) {
        const float r00 = p[m].wa * v[m][0].x + p[m].wb * v[m][0].y;
        const float r01 = p[m].wa * v[m][1].x + p[m].wb * v[m][1].y;
        const float r10 = p[m].wa * v[m][2].x + p[m].wb * v[m][2].y;
        const float r11 = p[m].wa * v[m][3].x + p[m].wb * v[m][3].y;
        const float res = p[m].wz0 * (p[m].wy0 * r00 + p[m].wy1 * r01)
                        + p[m].wz1 * (p[m].wy0 * r10 + p[m].wy1 * r11);
        __builtin_nontemporal_store(res, out + obase + m * L);
    }
}

extern "C" void kernel_launch(void* const* d_in, const int* in_sizes, int n_in,
                              void* d_out, int out_size, void* d_ws, size_t ws_size,
                              hipStream_t stream) {
    const float* rotmat = (const float*)d_in[0];
    const float* vol    = (const float*)d_in[1];
    float* out          = (float*)d_out;
    const int B = in_sizes[0] / 9;                // 2048

    const size_t need = TAB_BYTES + (size_t)SORT_N * 4;
    if (ws_size >= TAB_BYTES) {
        uint4* T  = (uint4*)d_ws;
        int* perm = (int*)((char*)d_ws + TAB_BYTES);
        const bool can_sort = (ws_size >= need) && (B % 8 == 0) && (B <= SORT_N);
        build_tab_sort<<<dim3(RANK_BLOCKS + TAB_BLOCKS), dim3(256), 0, stream>>>(
            vol, T, rotmat, perm, B, can_sort ? 1 : 0);
        const int nper = can_sort ? (B / 8) : 0;
        xfel_proj_t<<<dim3(16 * B), dim3(256), 0, stream>>>(rotmat, T, out,
                                                            perm, nper);
    } else {
        xfel_proj_f<<<dim3(16, B), dim3(256), 0, stream>>>(rotmat, vol, out);
    }
}

// Round 18
// 102.607 us; speedup vs baseline: 1.1763x; 1.1763x over previous
//
#include <hip/hip_runtime.h>

constexpr int L = 128;
constexpr int NVOX = L * L * L;                    // 2,097,152
constexpr size_t TAB_BYTES = (size_t)NVOX * 16;    // 32 MB packed table
constexpr int SORT_N = 2048;
constexpr int RANK_BLOCKS = SORT_N / 256;          // 8
constexpr int TAB_BLOCKS = NVOX / 256;             // 8192

union HU { unsigned short u; _Float16 h; };
typedef _Float16 h2v __attribute__((ext_vector_type(2)));
union H2U { unsigned int u; h2v h; };

__device__ __forceinline__ unsigned int pack2(float a, float b) {
    HU x, y; x.h = (_Float16)a; y.h = (_Float16)b;
    return (unsigned int)x.u | ((unsigned int)y.u << 16);
}
__device__ __forceinline__ h2v u2h2(unsigned int w) { H2U c; c.u = w; return c.h; }

// Brick swizzle: 64B line = 4 entries = 2x2 (x,y) patch at one z (R11: -17% FETCH).
__device__ __forceinline__ int brick_idx(int x, int y, int z) {
    return (z << 14) | ((y >> 1) << 8) | ((x >> 1) << 2) | ((y & 1) << 1) | (x & 1);
}

// ---- orientation key: Morton(octahedral(plane normal)) | index -------------
__device__ __forceinline__ unsigned part5(unsigned x) {   // 5-bit bit-spread
    x &= 0x1F;
    x = (x | (x << 4)) & 0x0F0Fu;
    x = (x | (x << 2)) & 0x3333u;
    x = (x | (x << 1)) & 0x5555u;
    return x;
}

__device__ __forceinline__ unsigned make_key(const float* __restrict__ R, int i)
{
    // plane normal = r0 x r2 (rows of R: r0 = j-direction, r2 = k-direction)
    float nx = R[1] * R[8] - R[2] * R[7];
    float ny = R[2] * R[6] - R[0] * R[8];
    float nz = R[0] * R[7] - R[1] * R[6];
    if (nz < 0.0f) { nx = -nx; ny = -ny; nz = -nz; }   // antipode fold
    const float s = fabsf(nx) + fabsf(ny) + nz + 1e-30f;
    const float u = nx / s, v = ny / s;                // octahedral hemisphere
    const int qu = min(max((int)((u * 0.5f + 0.5f) * 32.0f), 0), 31);
    const int qv = min(max((int)((v * 0.5f + 0.5f) * 32.0f), 0), 31);
    const unsigned morton = (part5((unsigned)qv) << 1) | part5((unsigned)qu);
    return (morton << 11) | (unsigned)i;               // unique -> deterministic
}

// ---- merged pre-pass -------------------------------------------------------
// Blocks 0..7 (dispatched FIRST): parallel rank-sort of the orientation keys.
//   rank_i = #{j: key_j < key_i} is a bijection (keys unique via index bits)
//   -> perm[rank_i] = i. ~2-3us across 8 blocks, overlaps the table build.
//   (R14 lesson: a single sort block at the grid TAIL serializes after the
//    build; at the HEAD it hides completely.)
// Blocks 8..8199: build T[e] = 2x2x2 fp16 stencil at (z,y,x), clamped-dup.
__global__ __launch_bounds__(256) void build_tab_sort(
    const float* __restrict__ vol, uint4* __restrict__ T,
    const float* __restrict__ rotmat, int* __restrict__ perm, int B, int do_sort)
{
    const int bid = blockIdx.x;
    const int tid = threadIdx.x;

    if (bid < RANK_BLOCKS) {
        if (!do_sort) return;
        __shared__ unsigned keys[SORT_N];
        #pragma unroll
        for (int h = 0; h < SORT_N / 256; ++h) {
            const int i = tid + h * 256;
            keys[i] = (i < B) ? make_key(rotmat + i * 9, i) : 0xFFFFFFFFu;
        }
        __syncthreads();
        const int img = (bid << 8) + tid;
        if (img < B) {
            const unsigned mykey = keys[img];
            int rank = 0;
            for (int j = 0; j < SORT_N; ++j)   // LDS broadcast scan
                rank += (keys[j] < mykey) ? 1 : 0;
            perm[rank] = img;
        }
        return;
    }

    const int e = (bid - RANK_BLOCKS) * 256 + tid;     // linear voxel id
    const int x  = e & 127, y = (e >> 7) & 127, z = e >> 14;
    const int x1 = min(x + 1, 127);
    const int ro0 = (y << 7), ro1 = (min(y + 1, 127) << 7);
    const float* __restrict__ p0 = vol + (z << 14);
    const float* __restrict__ p1 = vol + (min(z + 1, 127) << 14);
    uint4 o;
    o.x = pack2(p0[ro0 | x], p0[ro0 | x1]);
    o.y = pack2(p0[ro1 | x], p0[ro1 | x1]);
    o.z = pack2(p1[ro0 | x], p1[ro0 | x1]);
    o.w = pack2(p1[ro1 | x], p1[ro1 | x1]);
    T[brick_idx(x, y, z)] = o;
}

// ---------------- packed-table main kernel ----------------
struct Px {
    int e;            // bricked table index
    h2v wab;          // (xa,xb) as half2 -> fdot2 with table words
    float ya, yb, za, zb;
};

// slow path: full OOB/mask handling (edges of volume, annulus boundary)
__device__ __forceinline__ Px setup_slow(float gx, float gy, float gz, bool vis)
{
    Px p;
    const float fx0 = floorf(gx), fy0 = floorf(gy), fz0 = floorf(gz);
    const int ix = (int)fx0, iy = (int)fy0, iz = (int)fz0;
    const float fx = gx - fx0, fy = gy - fy0, fz = gz - fz0;

    const float wx0 = ((unsigned)ix       < 128u) ? 1.0f - fx : 0.0f;
    const float wx1 = ((unsigned)(ix + 1) < 128u) ? fx        : 0.0f;
    const float wy0 = ((unsigned)iy       < 128u) ? 1.0f - fy : 0.0f;
    const float wy1 = ((unsigned)(iy + 1) < 128u) ? fy        : 0.0f;
    const float wz0 = ((unsigned)iz       < 128u) ? 1.0f - fz : 0.0f;
    const float wz1 = ((unsigned)(iz + 1) < 128u) ? fz        : 0.0f;

    const float xa = (ix == -1) ? wx1 : wx0;
    const float xb = (ix == -1) ? 0.0f : wx1;
    p.wab = h2v{(_Float16)xa, (_Float16)xb};
    p.ya = (iy == -1) ? wy1 : wy0;  p.yb = (iy == -1) ? 0.0f : wy1;
    p.za = (iz == -1) ? wz1 : wz0;  p.zb = (iz == -1) ? 0.0f : wz1;
    if (!vis) { p.za = 0.0f; p.zb = 0.0f; }           // circular mask

    const bool alive = vis && (ix >= -1) && (ix <= 127) && (iy >= -1)
                           && (iy <= 127) && (iz >= -1) && (iz <= 127);
    const int xe = min(max(ix, 0), 127);
    const int ye = min(max(iy, 0), 127);
    const int ze = min(max(iz, 0), 127);
    p.e = alive ? brick_idx(xe, ye, ze) : 0;          // dead -> line 0
    return p;
}

// fast path: fully interior and visible -> no selects/clamps
__device__ __forceinline__ Px setup_fast(float gx, float gy, float gz)
{
    Px p;
    const float fx0 = floorf(gx), fy0 = floorf(gy), fz0 = floorf(gz);
    const float fx = gx - fx0, fy = gy - fy0, fz = gz - fz0;
    p.wab = h2v{(_Float16)(1.0f - fx), (_Float16)fx};
    p.ya = 1.0f - fy;  p.yb = fy;
    p.za = 1.0f - fz;  p.zb = fz;
    p.e = brick_idx((int)fx0, (int)fy0, (int)fz0);
    return p;
}

__device__ __forceinline__ float combine_px(const Px& p, uint4 W)
{
    const float d0 = __builtin_amdgcn_fdot2(u2h2(W.x), p.wab, 0.0f, false);
    const float d1 = __builtin_amdgcn_fdot2(u2h2(W.y), p.wab, 0.0f, false);
    const float d2 = __builtin_amdgcn_fdot2(u2h2(W.z), p.wab, 0.0f, false);
    const float d3 = __builtin_amdgcn_fdot2(u2h2(W.w), p.wab, 0.0f, false);
    return p.za * (p.ya * d0 + p.yb * d1) + p.zb * (p.ya * d2 + p.yb * d3);
}

// 1D grid + XCD-affine mapping over SORTED image order (R13: -23%).
__global__ __launch_bounds__(256) void xfel_proj_t(
    const float* __restrict__ rotmat,          // [B,3,3]
    const uint4* __restrict__ T,               // packed stencil table
    float* __restrict__ out,                   // [B,L,L]
    const int* __restrict__ perm,              // sorted pos -> image (or null)
    int nimg_per_xcd)                          // B/8 (0 -> identity mapping)
{
    const int n = blockIdx.x;
    int b, t;
    if (nimg_per_xcd > 0) {
        const int xcd = n & 7;
        const int s   = n >> 3;
        b = perm[xcd * nimg_per_xcd + (s >> 4)];
        t = s & 15;
    } else {
        b = n >> 4;
        t = n & 15;
    }

    const int tid  = threadIdx.x;
    const int lane = tid & 63;
    const int wv   = tid >> 6;                    // 0..3
    const int k    = ((t & 1) << 6) | lane;
    const int j0   = ((t >> 1) << 4) + (wv << 2); // rows j0..j0+3

    const int obase = (b * L + j0) * L + k;

    // circular mask
    const float stepw = 128.0f / 127.0f;
    const float ak  = (float)(k - 64) * stepw;
    const float ak2 = ak * ak;
    const float thr = 57.6f * 57.6f;              // (0.9*L/2)^2

    bool vis[4];
    bool all_vis = true, any_vis = false;
    #pragma unroll
    for (int m = 0; m < 4; ++m) {
        const float aj = (float)(j0 + m - 64) * stepw;
        vis[m] = (aj * aj + ak2 < thr);
        any_vis |= vis[m];
        all_vis &= vis[m];
    }
    if (__ballot((int)any_vis) == 0ull) {         // whole wave masked
        #pragma unroll
        for (int m = 0; m < 4; ++m)
            __builtin_nontemporal_store(0.0f, out + obase + m * L);
        return;
    }

    // rotation is block-uniform -> scalar loads
    const float* __restrict__ R = rotmat + b * 9;
    const float R00 = R[0], R01 = R[1], R02 = R[2];
    const float R10 = R[3], R11 = R[4], R12 = R[5];
    const float R20 = R[6], R21 = R[7], R22 = R[8];

    const float lk  = -1.0f + (float)k * (2.0f / 127.0f);
    const float yc  = -1.0f + 64.0f * (2.0f / 127.0f);  // lin[64]
    const float lj0 = -1.0f + (float)j0 * (2.0f / 127.0f);

    // voxel coords of row j0; per-row increment is exactly (R00,R01,R02)
    float gx = (lj0 * R00 + yc * R10 + lk * R20 + 1.0f) * 63.5f;
    float gy = (lj0 * R01 + yc * R11 + lk * R21 + 1.0f) * 63.5f;
    float gz = (lj0 * R02 + yc * R12 + lk * R22 + 1.0f) * 63.5f;

    // interior test: rows 0 and 3 bound the linear walk
    const float gx3 = gx + 3.0f * R00, gy3 = gy + 3.0f * R01, gz3 = gz + 3.0f * R02;
    const bool intr = all_vis
        && (gx  >= 0.0f) && (gx  < 127.0f) && (gx3 >= 0.0f) && (gx3 < 127.0f)
        && (gy  >= 0.0f) && (gy  < 127.0f) && (gy3 >= 0.0f) && (gy3 < 127.0f)
        && (gz  >= 0.0f) && (gz  < 127.0f) && (gz3 >= 0.0f) && (gz3 < 127.0f);

    Px p[4];
    if (__ballot((int)intr) == ~0ull) {
        // wave fully interior+visible (~93% of live waves)
        #pragma unroll
        for (int m = 0; m < 4; ++m) {
            p[m] = setup_fast(gx, gy, gz);
            gx += R00; gy += R01; gz += R02;
        }
    } else {
        bool any_alive = false;
        #pragma unroll
        for (int m = 0; m < 4; ++m) {
            p[m] = setup_slow(gx, gy, gz, vis[m]);
            any_alive |= (p[m].e != 0);
            gx += R00; gy += R01; gz += R02;
        }
        if (__ballot((int)any_alive) == 0ull) {   // whole wave dead
            #pragma unroll
            for (int m = 0; m < 4; ++m)
                __builtin_nontemporal_store(0.0f, out + obase + m * L);
            return;
        }
    }

    // 4 stencil gathers (one per pixel), all in flight before consumption
    uint4 W[4];
    #pragma unroll
    for (int m = 0; m < 4; ++m) W[m] = T[p[m].e];

    __builtin_amdgcn_sched_barrier(0);

    #pragma unroll
    for (int m = 0; m < 4; ++m) {
        const float res = combine_px(p[m], W[m]);
        __builtin_nontemporal_store(res, out + obase + m * L);
    }
}

// ---------------- fp32 fallback (R6 kernel) for small ws_size ----------------
typedef float f2v __attribute__((ext_vector_type(2), aligned(4)));

struct PxF {
    int b00, b01, b10, b11, xe;
    float wa, wb, wy0, wy1, wz0, wz1;
    bool alive;
};

__device__ __forceinline__ PxF setup_pxf(float gx, float gy, float gz, bool vis)
{
    PxF p;
    const float fx0 = floorf(gx), fy0 = floorf(gy), fz0 = floorf(gz);
    const int ix = (int)fx0, iy = (int)fy0, iz = (int)fz0;
    const float fx = gx - fx0, fy = gy - fy0, fz = gz - fz0;
    const float wx0 = ((unsigned)ix       < 128u) ? 1.0f - fx : 0.0f;
    const float wx1 = ((unsigned)(ix + 1) < 128u) ? fx        : 0.0f;
    p.wa = (ix == -1) ? wx1 : ((ix == 127) ? 0.0f : wx0);
    p.wb = (ix == 127) ? wx0 : ((ix == -1) ? 0.0f : wx1);
    p.wy0 = ((unsigned)iy       < 128u) ? 1.0f - fy : 0.0f;
    p.wy1 = ((unsigned)(iy + 1) < 128u) ? fy        : 0.0f;
    p.wz0 = (vis && (unsigned)iz       < 128u) ? 1.0f - fz : 0.0f;
    p.wz1 = (vis && (unsigned)(iz + 1) < 128u) ? fz        : 0.0f;
    p.alive = vis && (ix >= -1) && (ix <= 127) && (iy >= -1) && (iy <= 127)
                  && (iz >= -1) && (iz <= 127);
    int xe = min(max(ix, 0), 126);
    int y0 = min(max(iy, 0), 127), y1 = min(max(iy + 1, 0), 127);
    int z0 = min(max(iz, 0), 127), z1 = min(max(iz + 1, 0), 127);
    if (!p.alive) { xe = 0; y0 = 0; y1 = 0; z0 = 0; z1 = 0; }
    p.xe  = xe;
    p.b00 = (z0 << 14) | (y0 << 7);
    p.b01 = (z0 << 14) | (y1 << 7);
    p.b10 = (z1 << 14) | (y0 << 7);
    p.b11 = (z1 << 14) | (y1 << 7);
    return p;
}

__global__ __launch_bounds__(256) void xfel_proj_f(
    const float* __restrict__ rotmat,
    const float* __restrict__ vol,
    float* __restrict__ out)
{
    const int tid  = threadIdx.x;
    const int lane = tid & 63;
    const int wv   = tid >> 6;
    const int t    = blockIdx.x;
    const int b    = blockIdx.y;
    const int k    = ((t & 1) << 6) | lane;
    const int j0   = ((t >> 1) << 4) + (wv << 2);
    const int obase = (b * L + j0) * L + k;

    const float stepw = 128.0f / 127.0f;
    const float ak  = (float)(k - 64) * stepw;
    const float ak2 = ak * ak;
    const float thr = 57.6f * 57.6f;

    bool vis[4]; bool any_vis = false;
    #pragma unroll
    for (int m = 0; m < 4; ++m) {
        const float aj = (float)(j0 + m - 64) * stepw;
        vis[m] = (aj * aj + ak2 < thr);
        any_vis |= vis[m];
    }
    if (__ballot((int)any_vis) == 0ull) {
        #pragma unroll
        for (int m = 0; m < 4; ++m)
            __builtin_nontemporal_store(0.0f, out + obase + m * L);
        return;
    }

    const float* __restrict__ R = rotmat + b * 9;
    const float R00 = R[0], R01 = R[1], R02 = R[2];
    const float R10 = R[3], R11 = R[4], R12 = R[5];
    const float R20 = R[6], R21 = R[7], R22 = R[8];
    const float lk  = -1.0f + (float)k * (2.0f / 127.0f);
    const float yc  = -1.0f + 64.0f * (2.0f / 127.0f);
    const float lj0 = -1.0f + (float)j0 * (2.0f / 127.0f);

    float gx = (lj0 * R00 + yc * R10 + lk * R20 + 1.0f) * 63.5f;
    float gy = (lj0 * R01 + yc * R11 + lk * R21 + 1.0f) * 63.5f;
    float gz = (lj0 * R02 + yc * R12 + lk * R22 + 1.0f) * 63.5f;

    PxF p[4]; bool any_alive = false;
    #pragma unroll
    for (int m = 0; m < 4; ++m) {
        p[m] = setup_pxf(gx, gy, gz, vis[m]);
        any_alive |= p[m].alive;
        gx += R00; gy += R01; gz += R02;
    }
    if (__ballot((int)any_alive) == 0ull) {
        #pragma unroll
        for (int m = 0; m < 4; ++m)
            __builtin_nontemporal_store(0.0f, out + obase + m * L);
        return;
    }

    f2v v[4][4];
    #pragma unroll
    for (int m = 0; m < 4; ++m) {
        v[m][0] = *(const f2v*)(vol + p[m].b00 + p[m].xe);
        v[m][1] = *(const f2v*)(vol + p[m].b01 + p[m].xe);
        v[m][2] = *(const f2v*)(vol + p[m].b10 + p[m].xe);
        v[m][3] = *(const f2v*)(vol + p[m].b11 + p[m].xe);
    }
    __builtin_amdgcn_sched_barrier(0);

    #pragma unroll
    for (int m = 0; m < 4; ++m) {
        const float r00 = p[m].wa * v[m][0].x + p[m].wb * v[m][0].y;
        const float r01 = p[m].wa * v[m][1].x + p[m].wb * v[m][1].y;
        const float r10 = p[m].wa * v[m][2].x + p[m].wb * v[m][2].y;
        const float r11 = p[m].wa * v[m][3].x + p[m].wb * v[m][3].y;
        const float res = p[m].wz0 * (p[m].wy0 * r00 + p[m].wy1 * r01)
                        + p[m].wz1 * (p[m].wy0 * r10 + p[m].wy1 * r11);
        __builtin_nontemporal_store(res, out + obase + m * L);
    }
}

extern "C" void kernel_launch(void* const* d_in, const int* in_sizes, int n_in,
                              void* d_out, int out_size, void* d_ws, size_t ws_size,
                              hipStream_t stream) {
    const float* rotmat = (const float*)d_in[0];
    const float* vol    = (const float*)d_in[1];
    float* out          = (float*)d_out;
    const int B = in_sizes[0] / 9;                // 2048

    const size_t need = TAB_BYTES + (size_t)SORT_N * 4;
    if (ws_size >= TAB_BYTES) {
        uint4* T  = (uint4*)d_ws;
        int* perm = (int*)((char*)d_ws + TAB_BYTES);
        const bool can_sort = (ws_size >= need) && (B % 8 == 0) && (B <= SORT_N);
        build_tab_sort<<<dim3(RANK_BLOCKS + TAB_BLOCKS), dim3(256), 0, stream>>>(
            vol, T, rotmat, perm, B, can_sort ? 1 : 0);
        const int nper = can_sort ? (B / 8) : 0;
        xfel_proj_t<<<dim3(16 * B), dim3(256), 0, stream>>>(rotmat, T, out,
                                                            perm, nper);
    } else {
        xfel_proj_f<<<dim3(16, B), dim3(256), 0, stream>>>(rotmat, vol, out);
    }
}